// Round 2
// baseline (793.515 us; speedup 1.0000x reference)
//
#include <hip/hip_runtime.h>
#include <hip/hip_bf16.h>
#include <cstdint>
#include <cmath>

// ---------------------------------------------------------------------------
// Swin3D block: LN1 -> shift+window -> QKV -> win-attn(+relbias+mask) -> proj
//               -> unshift+residual -> LN2 -> FC1+GELU -> FC2 -> +residual
// Shapes: B=4, Z=16,H=32,W=32, C=384, heads=12, d=32, WS=4 (N=64), NW=256/b
// Workspace budget kept ~255 MB; fp32 residual x2 lives in d_out.
// ---------------------------------------------------------------------------

typedef __attribute__((ext_vector_type(4))) float f32x4;
typedef __attribute__((ext_vector_type(8))) __bf16 bf16x8_t;

static __device__ __forceinline__ short f2bf(float f) {
  unsigned u = __builtin_bit_cast(unsigned, f);
  unsigned lsb = (u >> 16) & 1u;
  u += 0x7fffu + lsb;
  return (short)(u >> 16);
}

static __device__ __forceinline__ void gload_lds16(const short* g, short* l) {
  __builtin_amdgcn_global_load_lds(
      (const __attribute__((address_space(1))) void*)g,
      (__attribute__((address_space(3))) void*)l, 16, 0, 0);
}

// ---------------- workspace layout (bytes), total ~255.2 MB ----------------
static constexpr size_t OFF_Q    = 0;
static constexpr size_t OFF_K    = 50331648;
static constexpr size_t OFF_V    = 100663296;                // qkv end 150994944
static constexpr size_t OFF_HID  = 0;                        // 201326592 B, over dead q/k/v
static constexpr size_t OFF_WIN  = 201326592;                // win / owin / h2 share (serial lives)
static constexpr size_t OFF_WQ   = OFF_WIN + 50331648;       // wqkv^T [1152][384]
static constexpr size_t OFF_WP   = OFF_WQ  + 884736;         // wproj^T [384][384]
static constexpr size_t OFF_W1   = OFF_WP  + 294912;         // wfc1^T [1536][384]
static constexpr size_t OFF_W2   = OFF_W1  + 1179648;        // wfc2^T [384][1536]
// end = OFF_W2 + 1179648 = 255197184

// ---------------- weight fp32 -> bf16 transpose ----------------
__global__ void k_w2bf_t(const float* __restrict__ w, short* __restrict__ wt,
                         int K, int N) {
  int idx = blockIdx.x * 256 + threadIdx.x;
  if (idx >= K * N) return;
  int k = idx / N, n = idx - k * N;
  wt[(size_t)n * K + k] = f2bf(w[idx]);
}

// ---------------- LN1 + roll(-2,-2,-2) + window partition -> bf16 ----------
__global__ __launch_bounds__(256) void k_ln1_window(
    const float* __restrict__ x, const float* __restrict__ gw,
    const float* __restrict__ gb, short* __restrict__ win) {
  int slot = blockIdx.x * 4 + (threadIdx.x >> 6);   // widx*64 + n, 0..65535
  int lane = threadIdx.x & 63;
  int widx = slot >> 6, n = slot & 63;
  int bidx = widx >> 8, wloc = widx & 255;
  int z = ((wloc >> 6) << 2) + (n >> 4);
  int h = (((wloc >> 3) & 7) << 2) + ((n >> 2) & 3);
  int w = ((wloc & 7) << 2) + (n & 3);
  int zs = (z + 2) & 15, hs = (h + 2) & 31, ws = (w + 2) & 31;
  const float* xp = x + ((size_t)bidx * 16384 + zs * 1024 + hs * 32 + ws) * 384;
  float v[6]; float s = 0.f, s2 = 0.f;
#pragma unroll
  for (int j = 0; j < 6; j++) {
    v[j] = xp[lane + j * 64];
    s += v[j]; s2 += v[j] * v[j];
  }
#pragma unroll
  for (int o = 1; o < 64; o <<= 1) { s += __shfl_xor(s, o); s2 += __shfl_xor(s2, o); }
  float mu = s * (1.f / 384.f);
  float rinv = rsqrtf(s2 * (1.f / 384.f) - mu * mu + 1e-5f);
  short* wp = win + (size_t)slot * 384;
#pragma unroll
  for (int j = 0; j < 6; j++) {
    int c = lane + j * 64;
    wp[c] = f2bf((v[j] - mu) * rinv * gw[c] + gb[c]);
  }
}

// ---------------- LN2 (plain, token order) -> bf16 ----------------
__global__ __launch_bounds__(256) void k_ln2(
    const float* __restrict__ x2, const float* __restrict__ gw,
    const float* __restrict__ gb, short* __restrict__ h2) {
  int t = blockIdx.x * 4 + (threadIdx.x >> 6);
  int lane = threadIdx.x & 63;
  const float* xp = x2 + (size_t)t * 384;
  float v[6]; float s = 0.f, s2 = 0.f;
#pragma unroll
  for (int j = 0; j < 6; j++) {
    v[j] = xp[lane + j * 64];
    s += v[j]; s2 += v[j] * v[j];
  }
#pragma unroll
  for (int o = 1; o < 64; o <<= 1) { s += __shfl_xor(s, o); s2 += __shfl_xor(s2, o); }
  float mu = s * (1.f / 384.f);
  float rinv = rsqrtf(s2 * (1.f / 384.f) - mu * mu + 1e-5f);
  short* hp = h2 + (size_t)t * 384;
#pragma unroll
  for (int j = 0; j < 6; j++) {
    int c = lane + j * 64;
    hp[c] = f2bf((v[j] - mu) * rinv * gw[c] + gb[c]);
  }
}

// ---------------- tiled bf16 MFMA GEMM: C = A[M][K] @ Bt[N][K]^T ------------
// 128x128 tile, BK=32, 256 thr (4 waves, each a 64x64 quadrant of 16x16 frags)
// EPI: 0=QKV scatter (q scaled, v transposed), 1=proj+unshift+residual->f32,
//      2=FC1+GELU->bf16, 3=FC2+residual->f32 out (in-place aux==of32 ok)
template <int EPI, int KDIM>
__global__ __launch_bounds__(256) void k_gemm(
    const short* __restrict__ A, const short* __restrict__ Bt,
    const float* __restrict__ bias, short* __restrict__ ob0,
    short* __restrict__ ob1, short* __restrict__ ob2,
    const float* __restrict__ aux, float* __restrict__ of32) {
  __shared__ short As[4096];
  __shared__ short Bs[4096];
  const int tid = threadIdx.x;
  const int wave = tid >> 6, lane = tid & 63;
  const int g = lane >> 4, li = lane & 15;
  const int m0 = blockIdx.y << 7, n0 = blockIdx.x << 7;
  const int c0 = wave * 2, c1 = c0 + 1;
  const int row0 = c0 * 16 + (lane >> 2), row1 = c1 * 16 + (lane >> 2);
  const int koff = (lane & 3) * 8;
  const short* gA0 = A + (size_t)(m0 + row0) * KDIM + koff;
  const short* gA1 = A + (size_t)(m0 + row1) * KDIM + koff;
  const short* gB0 = Bt + (size_t)(n0 + row0) * KDIM + koff;
  const short* gB1 = Bt + (size_t)(n0 + row1) * KDIM + koff;
  short* lA0 = As + c0 * 512; short* lA1 = As + c1 * 512;
  short* lB0 = Bs + c0 * 512; short* lB1 = Bs + c1 * 512;
  const int wm = wave >> 1, wn = wave & 1;
  const short* rA = As + (wm * 64 + li) * 32 + g * 8;
  const short* rB = Bs + (wn * 64 + li) * 32 + g * 8;
  f32x4 acc[4][4] = {};
  for (int kt = 0; kt < KDIM; kt += 32) {
    gload_lds16(gA0 + kt, lA0);
    gload_lds16(gA1 + kt, lA1);
    gload_lds16(gB0 + kt, lB0);
    gload_lds16(gB1 + kt, lB1);
    asm volatile("s_waitcnt vmcnt(0)" ::: "memory");
    __syncthreads();
    bf16x8_t a[4], b[4];
#pragma unroll
    for (int i = 0; i < 4; i++) a[i] = *(const bf16x8_t*)(rA + i * 512);
#pragma unroll
    for (int i = 0; i < 4; i++) b[i] = *(const bf16x8_t*)(rB + i * 512);
#pragma unroll
    for (int mi = 0; mi < 4; mi++)
#pragma unroll
      for (int ni = 0; ni < 4; ni++)
        acc[mi][ni] =
            __builtin_amdgcn_mfma_f32_16x16x32_bf16(a[mi], b[ni], acc[mi][ni], 0, 0, 0);
    __syncthreads();
  }
  // epilogue: row = m0+wm*64+mi*16+g*4+r ; col = n0+wn*64+ni*16+li
#pragma unroll
  for (int mi = 0; mi < 4; mi++) {
#pragma unroll
    for (int ni = 0; ni < 4; ni++) {
      const int col = n0 + wn * 64 + ni * 16 + li;
      const float bc = bias[col];
      const int rbase = m0 + wm * 64 + mi * 16 + g * 4;
      if constexpr (EPI == 0) {
        const int s = col / 384;
        const int rem = col - s * 384;
        const int head = rem >> 5, d = rem & 31;
#pragma unroll
        for (int r = 0; r < 4; r++) {
          const int row = rbase + r;
          const int widx = row >> 6, n = row & 63;
          float v = acc[mi][ni][r] + bc;
          if (s == 0)
            ob0[(((size_t)widx * 12 + head) * 64 + n) * 32 + d] =
                f2bf(v * 0.17677669529663687f);  // fold q scale (32^-1/2)
          else if (s == 1)
            ob1[(((size_t)widx * 12 + head) * 64 + n) * 32 + d] = f2bf(v);
          else  // v stored transposed: [widx][head][d][n]
            ob2[(((size_t)widx * 12 + head) * 32 + d) * 64 + n] = f2bf(v);
        }
      } else if constexpr (EPI == 1) {
#pragma unroll
        for (int r = 0; r < 4; r++) {
          const int row = rbase + r;
          const int widx = row >> 6, n = row & 63;
          const int wloc = widx & 255, bb = widx >> 8;
          const int z = ((wloc >> 6) << 2) + (n >> 4);
          const int h = (((wloc >> 3) & 7) << 2) + ((n >> 2) & 3);
          const int w = ((wloc & 7) << 2) + (n & 3);
          const int zs = (z + 2) & 15, hs = (h + 2) & 31, wsx = (w + 2) & 31;
          const size_t t = (size_t)bb * 16384 + zs * 1024 + hs * 32 + wsx;
          of32[t * 384 + col] = aux[t * 384 + col] + acc[mi][ni][r] + bc;
        }
      } else if constexpr (EPI == 2) {
#pragma unroll
        for (int r = 0; r < 4; r++) {
          const int row = rbase + r;
          float v = acc[mi][ni][r] + bc;
          ob0[(size_t)row * 1536 + col] =
              f2bf(0.5f * v * (1.f + erff(v * 0.70710678118654752f)));
        }
      } else {
#pragma unroll
        for (int r = 0; r < 4; r++) {
          const int row = rbase + r;
          of32[(size_t)row * 384 + col] =
              aux[(size_t)row * 384 + col] + acc[mi][ni][r] + bc;
        }
      }
    }
  }
}

// ---------------- windowed attention: 1 wave per (window, head) -------------
// S^T = mfma(K, Q) -> +relbias+mask -> column softmax -> LDS transpose -> P@V
__global__ __launch_bounds__(64) void k_attn(
    const short* __restrict__ qb, const short* __restrict__ kb,
    const short* __restrict__ vb, const float* __restrict__ relb,
    short* __restrict__ owin) {
  __shared__ short pt[64 * 80];  // [qn][kn], stride 80 (160B, 16B-aligned rows)
  const int wh_ = blockIdx.x;          // widx*12 + head
  const int widx = wh_ / 12, head = wh_ - widx * 12;
  const int lane = threadIdx.x;
  const int g = lane >> 4, li = lane & 15;
  const short* qp = qb + (size_t)wh_ * 2048;
  const short* kp = kb + (size_t)wh_ * 2048;
  const short* vp = vb + (size_t)wh_ * 2048;  // [d][n] layout
  bf16x8_t kf[4], qf[4];
#pragma unroll
  for (int t = 0; t < 4; t++) {
    kf[t] = *(const bf16x8_t*)(kp + (t * 16 + li) * 32 + g * 8);
    qf[t] = *(const bf16x8_t*)(qp + (t * 16 + li) * 32 + g * 8);
  }
  f32x4 zero = {0.f, 0.f, 0.f, 0.f};
  f32x4 st[4][4];  // [ti: kn-block][tj: qn-block]
#pragma unroll
  for (int ti = 0; ti < 4; ti++)
#pragma unroll
    for (int tj = 0; tj < 4; tj++)
      st[ti][tj] = __builtin_amdgcn_mfma_f32_16x16x32_bf16(kf[ti], qf[tj], zero, 0, 0, 0);
  const int wloc = widx & 255;
  const int wz = wloc >> 6, wh2 = (wloc >> 3) & 7, ww2 = wloc & 7;
#pragma unroll
  for (int tj = 0; tj < 4; tj++) {
    const int qn = tj * 16 + li;
    const int qz = qn >> 4, qh = (qn >> 2) & 3, qw = qn & 3;
    const int cq = ((wz < 3) ? 0 : ((qz < 2) ? 1 : 2)) * 9 +
                   ((wh2 < 7) ? 0 : ((qh < 2) ? 1 : 2)) * 3 +
                   ((ww2 < 7) ? 0 : ((qw < 2) ? 1 : 2));
    float mx = -1e30f;
#pragma unroll
    for (int ti = 0; ti < 4; ti++) {
#pragma unroll
      for (int r = 0; r < 4; r++) {
        const int kn = ti * 16 + g * 4 + r;
        const int kz = kn >> 4, kh = (kn >> 2) & 3, kw = kn & 3;
        const int ck = ((wz < 3) ? 0 : ((kz < 2) ? 1 : 2)) * 9 +
                       ((wh2 < 7) ? 0 : ((kh < 2) ? 1 : 2)) * 3 +
                       ((ww2 < 7) ? 0 : ((kw < 2) ? 1 : 2));
        const int idx = (qz - kz + 3) * 49 + (qh - kh + 3) * 7 + (qw - kw + 3);
        float v = st[ti][tj][r] + relb[idx * 12 + head] + ((ck == cq) ? 0.f : -100.f);
        st[ti][tj][r] = v;
        mx = fmaxf(mx, v);
      }
    }
    mx = fmaxf(mx, __shfl_xor(mx, 16));
    mx = fmaxf(mx, __shfl_xor(mx, 32));
    float sum = 0.f;
#pragma unroll
    for (int ti = 0; ti < 4; ti++)
#pragma unroll
      for (int r = 0; r < 4; r++) {
        float e = __expf(st[ti][tj][r] - mx);
        st[ti][tj][r] = e;
        sum += e;
      }
    sum += __shfl_xor(sum, 16);
    sum += __shfl_xor(sum, 32);
    const float rs = 1.f / sum;
#pragma unroll
    for (int ti = 0; ti < 4; ti++)
#pragma unroll
      for (int r = 0; r < 4; r++)
        pt[qn * 80 + ti * 16 + g * 4 + r] = f2bf(st[ti][tj][r] * rs);
  }
  __syncthreads();
  f32x4 o[4][2] = {};
#pragma unroll
  for (int kb2 = 0; kb2 < 2; kb2++) {
    bf16x8_t pa[4], bv[2];
#pragma unroll
    for (int tq = 0; tq < 4; tq++)
      pa[tq] = *(const bf16x8_t*)(pt + (tq * 16 + li) * 80 + kb2 * 32 + g * 8);
#pragma unroll
    for (int td = 0; td < 2; td++)
      bv[td] = *(const bf16x8_t*)(vp + (td * 16 + li) * 64 + kb2 * 32 + g * 8);
#pragma unroll
    for (int tq = 0; tq < 4; tq++)
#pragma unroll
      for (int td = 0; td < 2; td++)
        o[tq][td] = __builtin_amdgcn_mfma_f32_16x16x32_bf16(pa[tq], bv[td], o[tq][td], 0, 0, 0);
  }
#pragma unroll
  for (int tq = 0; tq < 4; tq++)
#pragma unroll
    for (int td = 0; td < 2; td++)
#pragma unroll
      for (int r = 0; r < 4; r++) {
        const int qn = tq * 16 + g * 4 + r;
        const int d = td * 16 + li;
        owin[((size_t)widx * 64 + qn) * 384 + head * 32 + d] = f2bf(o[tq][td][r]);
      }
}

// ---------------------------------------------------------------------------
extern "C" void kernel_launch(void* const* d_in, const int* in_sizes, int n_in,
                              void* d_out, int out_size, void* d_ws,
                              size_t ws_size, hipStream_t stream) {
  (void)in_sizes; (void)n_in; (void)out_size; (void)ws_size;
  const float* x      = (const float*)d_in[0];
  const float* n1g    = (const float*)d_in[1];
  const float* n1b    = (const float*)d_in[2];
  const float* qkv_w  = (const float*)d_in[3];
  const float* qkv_b  = (const float*)d_in[4];
  const float* proj_w = (const float*)d_in[5];
  const float* proj_b = (const float*)d_in[6];
  const float* relb   = (const float*)d_in[7];
  const float* n2g    = (const float*)d_in[8];
  const float* n2b    = (const float*)d_in[9];
  const float* fc1_w  = (const float*)d_in[10];
  const float* fc1_b  = (const float*)d_in[11];
  const float* fc2_w  = (const float*)d_in[12];
  const float* fc2_b  = (const float*)d_in[13];
  float* out = (float*)d_out;
  char* ws = (char*)d_ws;

  short* qbuf = (short*)(ws + OFF_Q);
  short* kbuf = (short*)(ws + OFF_K);
  short* vbuf = (short*)(ws + OFF_V);
  short* hid  = (short*)(ws + OFF_HID);
  short* win  = (short*)(ws + OFF_WIN);   // shared: win -> owin -> h2
  short* owin = (short*)(ws + OFF_WIN);
  short* h2   = (short*)(ws + OFF_WIN);
  float* x2   = out;                      // fp32 residual lives in d_out
  short* wq   = (short*)(ws + OFF_WQ);
  short* wp   = (short*)(ws + OFF_WP);
  short* w1   = (short*)(ws + OFF_W1);
  short* w2   = (short*)(ws + OFF_W2);

  // weights -> bf16 transposed [N][K]
  k_w2bf_t<<<(384 * 1152 + 255) / 256, 256, 0, stream>>>(qkv_w, wq, 384, 1152);
  k_w2bf_t<<<(384 * 384 + 255) / 256, 256, 0, stream>>>(proj_w, wp, 384, 384);
  k_w2bf_t<<<(384 * 1536 + 255) / 256, 256, 0, stream>>>(fc1_w, w1, 384, 1536);
  k_w2bf_t<<<(1536 * 384 + 255) / 256, 256, 0, stream>>>(fc2_w, w2, 1536, 384);

  // LN1 + shift + window partition
  k_ln1_window<<<16384, 256, 0, stream>>>(x, n1g, n1b, win);
  // QKV GEMM [65536,384]@[384,1152]
  k_gemm<0, 384><<<dim3(9, 512), 256, 0, stream>>>(win, wq, qkv_b, qbuf, kbuf,
                                                   vbuf, nullptr, nullptr);
  // windowed attention
  k_attn<<<1024 * 12, 64, 0, stream>>>(qbuf, kbuf, vbuf, relb, owin);
  // proj GEMM + unshift + residual -> x2 (in d_out)
  k_gemm<1, 384><<<dim3(3, 512), 256, 0, stream>>>(owin, wp, proj_b, nullptr,
                                                   nullptr, nullptr, x, x2);
  // LN2
  k_ln2<<<16384, 256, 0, stream>>>(x2, n2g, n2b, h2);
  // FC1 + GELU
  k_gemm<2, 384><<<dim3(12, 512), 256, 0, stream>>>(h2, w1, fc1_b, hid, nullptr,
                                                    nullptr, nullptr, nullptr);
  // FC2 + residual -> out (in-place: aux == of32 == d_out)
  k_gemm<3, 1536><<<dim3(3, 512), 256, 0, stream>>>(hid, w2, fc2_b, nullptr,
                                                    nullptr, nullptr, x2, out);
}